// Round 4
// baseline (271.913 us; speedup 1.0000x reference)
//
#include <hip/hip_runtime.h>
#include <hip/hip_bf16.h>
#include <stdint.h>

#define EMBED 1024
#define HEADS 16
#define CTX   2048
#define BATCH 4
#define HD    64
#define M_TOT (BATCH*CTX)   // 8192

typedef unsigned short u16;
typedef __attribute__((ext_vector_type(8))) short short8;   // 8 bf16 (4 VGPRs)
typedef __attribute__((ext_vector_type(4))) float floatx4;  // MFMA C/D

typedef const __attribute__((address_space(1))) unsigned int g_u32;
typedef __attribute__((address_space(3))) unsigned int l_u32;

__device__ __forceinline__ void async16(const void* g, void* l) {
    __builtin_amdgcn_global_load_lds((g_u32*)g, (l_u32*)l, 16, 0, 0);
}

__device__ __forceinline__ u16 f2bf(float f) {          // round-nearest-even
    uint32_t u = __float_as_uint(f);
    uint32_t r = (u + 0x7FFFu + ((u >> 16) & 1u)) >> 16;
    return (u16)r;
}

// ---------------- fused fp32 -> bf16 convert (x + 4 weight matrices, 1 launch) ----------------
__global__ void cvt_all(const float* __restrict__ x,
                        const float* __restrict__ Wq, const float* __restrict__ Wk,
                        const float* __restrict__ Wv, const float* __restrict__ Wp,
                        u16* __restrict__ xb,
                        u16* __restrict__ wqb, u16* __restrict__ wkb,
                        u16* __restrict__ wvb, u16* __restrict__ wpb) {
    const int b = blockIdx.x;
    const float* src; u16* dst; int base;
    if (b < 8192)       { src = x;  dst = xb;  base = b; }
    else if (b < 9216)  { src = Wq; dst = wqb; base = b - 8192; }
    else if (b < 10240) { src = Wk; dst = wkb; base = b - 9216; }
    else if (b < 11264) { src = Wv; dst = wvb; base = b - 10240; }
    else                { src = Wp; dst = wpb; base = b - 11264; }
    const int i = (base * 256 + threadIdx.x) * 4;
    float4 f = *(const float4*)(src + i);
    ushort4 o;
    o.x = f2bf(f.x); o.y = f2bf(f.y); o.z = f2bf(f.z); o.w = f2bf(f.w);
    *(ushort4*)(dst + i) = o;
}

// ================= fused QKV GEMM, 128x128 tile, BK=64 (R0-verified structure) =================
__global__ __launch_bounds__(256)
void gemm_qkv(const u16* __restrict__ A,
              const u16* __restrict__ Wq, const u16* __restrict__ Wk, const u16* __restrict__ Wv,
              const float* __restrict__ bq, const float* __restrict__ bk, const float* __restrict__ bv,
              u16* __restrict__ oq, u16* __restrict__ ok, u16* __restrict__ ov,
              float qscale)
{
    __shared__ u16 As[128*64];   // 16 KB
    __shared__ u16 Bs[128*64];   // 16 KB
    const int tid  = threadIdx.x;
    const int lane = tid & 63;
    const int wid  = tid >> 6;
    const int wm = wid >> 1, wn = wid & 1;
    const int quad = lane >> 4;
    const int l16  = lane & 15;
    const int bm0 = blockIdx.x * 128;
    const int sel = blockIdx.y >> 3;          // 0=Q 1=K 2=V
    const int bn0 = (blockIdx.y & 7) * 128;

    const u16*  Bw   = (sel == 0) ? Wq : (sel == 1) ? Wk : Wv;
    const float* bias = (sel == 0) ? bq : (sel == 1) ? bk : bv;
    u16*        out  = (sel == 0) ? oq : (sel == 1) ? ok : ov;
    const float scale = (sel == 0) ? qscale : 1.0f;

    floatx4 acc[4][4] = {};

    const int r0   = tid >> 3;
    const int joff = ((tid & 7) ^ ((tid >> 3) & 7)) * 8;   // shorts
    const u16* Ag0 = A  + (size_t)(bm0 + r0      ) * EMBED + joff;
    const u16* Ag1 = A  + (size_t)(bm0 + r0 + 32 ) * EMBED + joff;
    const u16* Ag2 = A  + (size_t)(bm0 + r0 + 64 ) * EMBED + joff;
    const u16* Ag3 = A  + (size_t)(bm0 + r0 + 96 ) * EMBED + joff;
    const u16* Bg0 = Bw + (size_t)(bn0 + r0      ) * EMBED + joff;
    const u16* Bg1 = Bw + (size_t)(bn0 + r0 + 32 ) * EMBED + joff;
    const u16* Bg2 = Bw + (size_t)(bn0 + r0 + 64 ) * EMBED + joff;
    const u16* Bg3 = Bw + (size_t)(bn0 + r0 + 96 ) * EMBED + joff;
    char* AsB = (char*)As;
    char* BsB = (char*)Bs;
    const int wbyte = wid * 1024;

    const int fpos0 = (quad ^ (l16 & 7)) * 8;
    const int fpos1 = fpos0 ^ 32;

    for (int kk = 0; kk < EMBED; kk += 64) {
        __syncthreads();
        async16(Ag0 + kk, AsB + wbyte);
        async16(Ag1 + kk, AsB + wbyte + 4096);
        async16(Ag2 + kk, AsB + wbyte + 8192);
        async16(Ag3 + kk, AsB + wbyte + 12288);
        async16(Bg0 + kk, BsB + wbyte);
        async16(Bg1 + kk, BsB + wbyte + 4096);
        async16(Bg2 + kk, BsB + wbyte + 8192);
        async16(Bg3 + kk, BsB + wbyte + 12288);
        __syncthreads();

#pragma unroll
        for (int ks = 0; ks < 2; ks++) {
            const int fp = ks ? fpos1 : fpos0;
            short8 a[4], b[4];
#pragma unroll
            for (int i = 0; i < 4; i++)
                a[i] = *(const short8*)(As + (wm*64 + i*16 + l16)*64 + fp);
#pragma unroll
            for (int i = 0; i < 4; i++)
                b[i] = *(const short8*)(Bs + (wn*64 + i*16 + l16)*64 + fp);
#pragma unroll
            for (int i = 0; i < 4; i++)
#pragma unroll
                for (int j = 0; j < 4; j++)
                    acc[i][j] = __builtin_amdgcn_mfma_f32_16x16x32_bf16(a[i], b[j], acc[i][j], 0, 0, 0);
        }
    }

#pragma unroll
    for (int i = 0; i < 4; i++) {
#pragma unroll
        for (int j = 0; j < 4; j++) {
            const int col = bn0 + wn*64 + j*16 + l16;
            const float bvv = bias[col];
#pragma unroll
            for (int r = 0; r < 4; r++) {
                const int row = bm0 + wm*64 + i*16 + quad*4 + r;
                const float v = (acc[i][j][r] + bvv) * scale;
                const int bb = row >> 11, t = row & 2047;
                const int hh = col >> 6,  d = col & 63;
                if (sel != 2)
                    out[((size_t)(bb*HEADS + hh)*CTX + t)*HD + d] = f2bf(v);
                else
                    out[((size_t)(bb*HEADS + hh)*HD + d)*CTX + t] = f2bf(v);
            }
        }
    }
}

// ================= projection GEMM (fp32 out), BK=64, ping-pong double-buffer =================
// Same staging pattern as attn_kernel (verified): one __syncthreads per iter;
// stage(kt+1)->buf^1 issued right after it, overlapping compute(buf). The
// barrier's implicit vmcnt(0)/lgkmcnt(0) drain covers both hazards.
__global__ __launch_bounds__(256)
void gemm_proj(const u16* __restrict__ A, const u16* __restrict__ Bw,
               const float* __restrict__ bias, float* __restrict__ out)
{
    __shared__ u16 As[2][128*64];   // 2 x 16 KB
    __shared__ u16 Bs[2][128*64];   // 2 x 16 KB
    const int tid  = threadIdx.x;
    const int lane = tid & 63;
    const int wid  = tid >> 6;
    const int wm = wid >> 1, wn = wid & 1;
    const int quad = lane >> 4;
    const int l16  = lane & 15;
    const int bm0 = blockIdx.x * 128;
    const int bn0 = blockIdx.y * 128;

    floatx4 acc[4][4] = {};

    const int r0   = tid >> 3;
    const int joff = ((tid & 7) ^ ((tid >> 3) & 7)) * 8;
    const u16* Ag0 = A  + (size_t)(bm0 + r0      ) * EMBED + joff;
    const u16* Ag1 = A  + (size_t)(bm0 + r0 + 32 ) * EMBED + joff;
    const u16* Ag2 = A  + (size_t)(bm0 + r0 + 64 ) * EMBED + joff;
    const u16* Ag3 = A  + (size_t)(bm0 + r0 + 96 ) * EMBED + joff;
    const u16* Bg0 = Bw + (size_t)(bn0 + r0      ) * EMBED + joff;
    const u16* Bg1 = Bw + (size_t)(bn0 + r0 + 32 ) * EMBED + joff;
    const u16* Bg2 = Bw + (size_t)(bn0 + r0 + 64 ) * EMBED + joff;
    const u16* Bg3 = Bw + (size_t)(bn0 + r0 + 96 ) * EMBED + joff;
    const int wbyte = wid * 1024;
    const int fpos0 = (quad ^ (l16 & 7)) * 8;
    const int fpos1 = fpos0 ^ 32;

    auto stage = [&](int it, int buf) {
        char* AsB = (char*)As + buf * 16384;
        char* BsB = (char*)Bs + buf * 16384;
        const int kk = it * 64;
        async16(Ag0 + kk, AsB + wbyte);
        async16(Ag1 + kk, AsB + wbyte + 4096);
        async16(Ag2 + kk, AsB + wbyte + 8192);
        async16(Ag3 + kk, AsB + wbyte + 12288);
        async16(Bg0 + kk, BsB + wbyte);
        async16(Bg1 + kk, BsB + wbyte + 4096);
        async16(Bg2 + kk, BsB + wbyte + 8192);
        async16(Bg3 + kk, BsB + wbyte + 12288);
    };

    int buf = 0;
    stage(0, 0);

#pragma unroll 1
    for (int it = 0; it < EMBED/64; ++it) {
        __syncthreads();                    // drains stage(it) (issued last iter)
        if (it + 1 < EMBED/64) stage(it + 1, buf ^ 1);

        const u16* Ac = &As[buf][0];
        const u16* Bc = &Bs[buf][0];
#pragma unroll
        for (int ks = 0; ks < 2; ks++) {
            const int fp = ks ? fpos1 : fpos0;
            short8 a[4], b[4];
#pragma unroll
            for (int i = 0; i < 4; i++)
                a[i] = *(const short8*)(Ac + (wm*64 + i*16 + l16)*64 + fp);
#pragma unroll
            for (int i = 0; i < 4; i++)
                b[i] = *(const short8*)(Bc + (wn*64 + i*16 + l16)*64 + fp);
#pragma unroll
            for (int i = 0; i < 4; i++)
#pragma unroll
                for (int j = 0; j < 4; j++)
                    acc[i][j] = __builtin_amdgcn_mfma_f32_16x16x32_bf16(a[i], b[j], acc[i][j], 0, 0, 0);
        }
        buf ^= 1;
    }

#pragma unroll
    for (int i = 0; i < 4; i++) {
#pragma unroll
        for (int j = 0; j < 4; j++) {
            const int col = bn0 + wn*64 + j*16 + l16;
            const float bvv = bias[col];
#pragma unroll
            for (int r = 0; r < 4; r++) {
                const int row = bm0 + wm*64 + i*16 + quad*4 + r;
                out[(size_t)row * EMBED + col] = acc[i][j][r] + bvv;
            }
        }
    }
}

// ---------------- flash attention: 64 q/block (16 rows/wave), S^T order, swizzled P ----------------
// Occupancy-oriented re-tile of the verified 128-q kernel: each wave runs the
// exact st=0 sub-case of the old code. Grid 1024 (XCD-grouped): xcd=lid&7,
// 8 bh each, bx 0..15 pairs q-tiles (bx, 31-bx) of 64 rows -> constant 33
// key-tiles/block. LDS 40 KB -> 4 blocks/CU (was 2), 16 waves/CU.
__global__ __launch_bounds__(256)
void attn_kernel(const u16* __restrict__ Q, const u16* __restrict__ K,
                 const u16* __restrict__ Vt, u16* __restrict__ O)
{
    __shared__ u16 Ks[2][64*64];     // 2 x 8 KB
    __shared__ u16 Vs[2][64*64];     // 2 x 8 KB   Vs[d][ki]
    __shared__ u16 Ps[4*16*64];      // 8 KB, per-wave 16 rows x 64 ki

    const int tid  = threadIdx.x, lane = tid & 63, w = tid >> 6;
    const int quad = lane >> 4, l16 = lane & 15;

    const int lid  = blockIdx.x;            // 0..1023
    const int xcd  = lid & 7;
    const int slot = lid >> 3;              // 0..127
    const int bh   = xcd * 8 + (slot >> 4); // 0..63
    const int bx   = slot & 15;             // 0..15
    const int h    = bh & (HEADS - 1);
    const int b    = bh >> 4;

    const u16* Qh = Q  + (size_t)bh * CTX * HD;
    const u16* Kh = K  + (size_t)bh * CTX * HD;
    const u16* Vh = Vt + (size_t)bh * HD * CTX;

    const int srow = tid >> 3;
    const int joff = ((tid & 7) ^ (srow & 7)) * 8;
    const int wbyte = w * 1024;
    char* PwB = (char*)(Ps + w * 16 * 64);
    const int sw = l16 & 7;                 // swizzle key (row&7 for all our rows)

    auto stage = [&](int kt, int buf) {
        char* kb = (char*)(&Ks[buf][0]) + wbyte;
        char* vb = (char*)(&Vs[buf][0]) + wbyte;
        async16(Kh + (size_t)(kt*64 + srow     )*HD + joff, kb);
        async16(Kh + (size_t)(kt*64 + srow + 32)*HD + joff, kb + 4096);
        async16(Vh + (size_t)(srow     )*CTX + kt*64 + joff, vb);
        async16(Vh + (size_t)(srow + 32)*CTX + kt*64 + joff, vb + 4096);
    };

    int par = 0;
    stage(0, 0);

#pragma unroll 1
    for (int pass = 0; pass < 2; pass++) {
        const int qb  = (pass == 0) ? bx : (31 - bx);
        const int qb0 = qb * 64;
        const int KT  = qb + 1;

        // Q fragments (B-operand: n=q=l16, k=d): qf[kstep]
        short8 qf[2];
#pragma unroll
        for (int ks = 0; ks < 2; ks++)
            qf[ks] = *(const short8*)(Qh + (size_t)(qb0 + w*16 + l16)*HD + ks*32 + quad*8);

        float lsum = 0.f;
        floatx4 o_acc[4] = {};

        for (int kt = 0; kt < KT; kt++) {
            __syncthreads();   // drains stage(kt), in flight since previous compute

            if (kt + 1 < KT)      stage(kt + 1, par ^ 1);
            else if (pass == 0)   stage(0,      par ^ 1);

            const char* KcB = (const char*)(&Ks[par][0]);
            const char* VcB = (const char*)(&Vs[par][0]);

            // S^T = K Q^T : m=ki (row=quad*4+r), n=q (col=l16)
            floatx4 s[4] = {};
#pragma unroll
            for (int ks = 0; ks < 2; ks++) {
#pragma unroll
                for (int ni = 0; ni < 4; ni++) {
                    short8 kf = *(const short8*)(KcB + (ni*16 + l16)*128
                                                 + (((4*ks + quad) ^ sw) * 16));
                    s[ni] = __builtin_amdgcn_mfma_f32_16x16x32_bf16(kf, qf[ks], s[ni], 0, 0, 0);
                }
            }

            // P = exp2(S'), mask on diagonal tile, packed b64 stores to swizzled P
            const bool mt = (kt == qb);
            const int key0 = kt * 64;
            const int qrow = qb0 + w*16 + l16;
#pragma unroll
            for (int ni = 0; ni < 4; ni++) {
                float p[4];
#pragma unroll
                for (int r = 0; r < 4; r++) {
                    float v = s[ni][r];
                    if (mt) {
                        const int key = key0 + ni*16 + quad*4 + r;
                        if (key > qrow) v = -INFINITY;
                    }
                    p[r] = __builtin_amdgcn_exp2f(v);
                    lsum += p[r];
                }
                uint2 pk;
                pk.x = (__float_as_uint(p[0]) >> 16) | (__float_as_uint(p[1]) & 0xFFFF0000u);
                pk.y = (__float_as_uint(p[2]) >> 16) | (__float_as_uint(p[3]) & 0xFFFF0000u);
                *(uint2*)(PwB + l16*128
                          + (((2*ni + (quad >> 1)) ^ sw) * 16) + (quad & 1) * 8) = pk;
            }

            // O += P V : A=P (m=q), B=Vt rows (n=d, k=ki)
#pragma unroll
            for (int ks = 0; ks < 2; ks++) {
                const int pco = ((4*ks + quad) ^ sw) * 16;
                short8 pf = *(const short8*)(PwB + l16*128 + pco);
#pragma unroll
                for (int ni = 0; ni < 4; ni++) {
                    short8 vf = *(const short8*)(VcB + (ni*16 + l16)*128 + pco);
                    o_acc[ni] = __builtin_amdgcn_mfma_f32_16x16x32_bf16(pf, vf, o_acc[ni], 0, 0, 0);
                }
            }

            par ^= 1;
        }

        // l-sum: reduce across the 4 quads (lane l has sum for q=l&15), then
        // redistribute reciprocal to the C-layout lanes (q = quad*4+r).
        float linv[4];
        lsum += __shfl_xor(lsum, 16);
        lsum += __shfl_xor(lsum, 32);
        const float rinv = 1.f / lsum;
#pragma unroll
        for (int r = 0; r < 4; r++)
            linv[r] = __shfl(rinv, quad*4 + r);

        u16* Ob = O + ((size_t)b * CTX) * EMBED + (size_t)h * HD;
#pragma unroll
        for (int ni = 0; ni < 4; ni++)
#pragma unroll
            for (int r = 0; r < 4; r++) {
                const int qrow = qb0 + w*16 + quad*4 + r;
                Ob[(size_t)qrow * EMBED + ni*16 + l16] = f2bf(o_acc[ni][r] * linv[r]);
            }
    }
}

// ---------------- launcher ----------------
extern "C" void kernel_launch(void* const* d_in, const int* in_sizes, int n_in,
                              void* d_out, int out_size, void* d_ws, size_t ws_size,
                              hipStream_t stream) {
    const float* x  = (const float*)d_in[0];
    const float* Wq = (const float*)d_in[1];
    const float* bq = (const float*)d_in[2];
    const float* Wk = (const float*)d_in[3];
    const float* bk = (const float*)d_in[4];
    const float* Wv = (const float*)d_in[5];
    const float* bv = (const float*)d_in[6];
    const float* Wp = (const float*)d_in[7];
    const float* bp = (const float*)d_in[8];

    char* ws = (char*)d_ws;
    const size_t XSZ = (size_t)M_TOT * EMBED * 2;   // 16 MB
    const size_t WSZ = (size_t)EMBED * EMBED * 2;   // 2 MB
    u16* xb  = (u16*)ws;                 ws += XSZ;
    u16* wqb = (u16*)ws;                 ws += WSZ;
    u16* wkb = (u16*)ws;                 ws += WSZ;
    u16* wvb = (u16*)ws;                 ws += WSZ;
    u16* wpb = (u16*)ws;                 ws += WSZ;
    u16* qg  = (u16*)ws;                 ws += XSZ;
    u16* kg  = (u16*)ws;                 ws += XSZ;
    u16* vtg = (u16*)ws;                 ws += XSZ;
    u16* og  = xb;   // x-bf16 dead after QKV GEMM; attn output reuses it

    cvt_all<<<12288, 256, 0, stream>>>(x, Wq, Wk, Wv, Wp, xb, wqb, wkb, wvb, wpb);

    const float qscale = 0.125f * 1.44269504f;  // 1/sqrt(64) * log2(e)
    gemm_qkv<<<dim3(M_TOT/128, 24), 256, 0, stream>>>(xb, wqb, wkb, wvb, bq, bk, bv,
                                                      qg, kg, vtg, qscale);

    attn_kernel<<<dim3(1024), 256, 0, stream>>>(qg, kg, vtg, og);

    gemm_proj<<<dim3(M_TOT/128, EMBED/128), 256, 0, stream>>>(og, wpb, bp, (float*)d_out);
}